// Round 14
// baseline (19181.584 us; speedup 1.0000x reference)
//
#include <hip/hip_runtime.h>

__host__ __device__ static inline int cdiv(int a, int b) { return (a + b - 1) / b; }

#define GBK 16

// split-K / matvec-partial workspace (set per kernel_launch; deterministic)
static float* g_ps = nullptr;
static long long g_ps_cap = 0;   // capacity in floats
static int g_ps_ok = 0;

// ---------------------------------------------------------------------------
// GEMM: C = alpha * opA(A) opB(B) + (Add?Add:0) + (addI?I:0)
// OPA==0: A is MxK row-major.  OPA==1: A physical KxM; opA[m,k]=A[k*lda+m]
// OPB==0: B is KxN row-major.  OPB==1: B physical NxK; opB[k,n]=B[n*ldb+k]
// sym!=0: skip blocks with col-block > row-block.
// 128x128 tile, 256 threads, 8x8 microtile, double-buffered LDS.
// __launch_bounds__(256,3): cap VGPR<=168 -> 3 waves/SIMD, 3 blocks/CU.
// LDS:FMA cycle ratio 1:1 (2048:2048 per K-step) -> both pipes saturable.
// Per-element K-order: ascending-k fmaf chain (bitwise = previous kernels).
// REQUIRES: M,N multiples of 128; K multiple of 16; 16B-aligned pointers.
// ---------------------------------------------------------------------------
template<int OPA, int OPB>
__global__ void __launch_bounds__(256, 3)
gemm_kernel(int M, int N, int K,
            const float* __restrict__ A, int lda,
            const float* __restrict__ B, int ldb,
            float* __restrict__ C, int ldc,
            float alpha,
            const float* __restrict__ Add, int ldadd, int addI,
            size_t zsA, size_t zsB, size_t zsC, int sym)
{
  if (sym && (int)blockIdx.x > (int)blockIdx.y) return;
  constexpr int TMp = 128, TNp = 128, PAD = 4;
  A += (size_t)blockIdx.z * zsA;
  B += (size_t)blockIdx.z * zsB;
  C += (size_t)blockIdx.z * zsC;
  __shared__ float As[2][GBK][TMp + PAD];
  __shared__ float Bs[2][GBK][TNp + PAD];
  const int tid = (int)threadIdx.x;
  const int tx = tid & 15;
  const int ty = tid >> 4;
  const int bm = (int)blockIdx.y * TMp;
  const int bn = (int)blockIdx.x * TNp;

  // staging: 2 float4 per thread per operand
  const int arow = tid >> 2, aq = tid & 3;   // transpose staging (row-major src)
  const int akk = tid >> 5, amc = tid & 31;  // direct staging

  float4 ra[2], rb[2];
  auto loadA = [&](int k0) {
#pragma unroll
    for (int l = 0; l < 2; ++l) {
      if (OPA == 0) ra[l] = *reinterpret_cast<const float4*>(&A[(size_t)(bm + arow + 64 * l) * lda + k0 + aq * 4]);
      else          ra[l] = *reinterpret_cast<const float4*>(&A[(size_t)(k0 + akk + 8 * l) * lda + bm + amc * 4]);
    }
  };
  auto storeA = [&](int buf) {
#pragma unroll
    for (int l = 0; l < 2; ++l) {
      if (OPA == 0) {
        As[buf][aq * 4 + 0][arow + 64 * l] = ra[l].x; As[buf][aq * 4 + 1][arow + 64 * l] = ra[l].y;
        As[buf][aq * 4 + 2][arow + 64 * l] = ra[l].z; As[buf][aq * 4 + 3][arow + 64 * l] = ra[l].w;
      } else {
        *reinterpret_cast<float4*>(&As[buf][akk + 8 * l][amc * 4]) = ra[l];
      }
    }
  };
  auto loadB = [&](int k0) {
#pragma unroll
    for (int l = 0; l < 2; ++l) {
      if (OPB == 0) rb[l] = *reinterpret_cast<const float4*>(&B[(size_t)(k0 + akk + 8 * l) * ldb + bn + amc * 4]);
      else          rb[l] = *reinterpret_cast<const float4*>(&B[(size_t)(bn + arow + 64 * l) * ldb + k0 + aq * 4]);
    }
  };
  auto storeB = [&](int buf) {
#pragma unroll
    for (int l = 0; l < 2; ++l) {
      if (OPB == 0) {
        *reinterpret_cast<float4*>(&Bs[buf][akk + 8 * l][amc * 4]) = rb[l];
      } else {
        Bs[buf][aq * 4 + 0][arow + 64 * l] = rb[l].x; Bs[buf][aq * 4 + 1][arow + 64 * l] = rb[l].y;
        Bs[buf][aq * 4 + 2][arow + 64 * l] = rb[l].z; Bs[buf][aq * 4 + 3][arow + 64 * l] = rb[l].w;
      }
    }
  };

  float acc[8][8];
#pragma unroll
  for (int i = 0; i < 8; ++i)
#pragma unroll
    for (int j = 0; j < 8; ++j) acc[i][j] = 0.f;

  const int nk = K / GBK;
  loadA(0); loadB(0); storeA(0); storeB(0);
  __syncthreads();

  for (int t = 0; t < nk; ++t) {
    const int cur = t & 1;
    if (t + 1 < nk) { loadA((t + 1) * GBK); loadB((t + 1) * GBK); }
#pragma unroll
    for (int kk = 0; kk < GBK; ++kk) {
      float a[8], b[8];
      *reinterpret_cast<float4*>(&a[0]) = *reinterpret_cast<const float4*>(&As[cur][kk][ty * 4]);
      *reinterpret_cast<float4*>(&a[4]) = *reinterpret_cast<const float4*>(&As[cur][kk][64 + ty * 4]);
      *reinterpret_cast<float4*>(&b[0]) = *reinterpret_cast<const float4*>(&Bs[cur][kk][tx * 4]);
      *reinterpret_cast<float4*>(&b[4]) = *reinterpret_cast<const float4*>(&Bs[cur][kk][64 + tx * 4]);
#pragma unroll
      for (int i = 0; i < 8; ++i)
#pragma unroll
        for (int j = 0; j < 8; ++j)
          acc[i][j] = fmaf(a[i], b[j], acc[i][j]);
    }
    if (t + 1 < nk) { storeA(cur ^ 1); storeB(cur ^ 1); }
    __syncthreads();
  }

#pragma unroll
  for (int i = 0; i < 8; ++i) {
    const int gm = bm + ((i < 4) ? (ty * 4 + i) : (64 + ty * 4 + i - 4));
#pragma unroll
    for (int g = 0; g < 2; ++g) {
      const int gn0 = bn + g * 64 + tx * 4;
      float vv[4];
#pragma unroll
      for (int j = 0; j < 4; ++j) vv[j] = alpha * acc[i][g * 4 + j];
      if (Add) {
        const float4 ad = *reinterpret_cast<const float4*>(&Add[(size_t)gm * ldadd + gn0]);
        vv[0] += ad.x; vv[1] += ad.y; vv[2] += ad.z; vv[3] += ad.w;
      }
      if (addI) {
#pragma unroll
        for (int j = 0; j < 4; ++j) if (gm == gn0 + j) vv[j] += 1.f;
      }
      float4 v; v.x = vv[0]; v.y = vv[1]; v.z = vv[2]; v.w = vv[3];
      *reinterpret_cast<float4*>(&C[(size_t)gm * ldc + gn0]) = v;
    }
  }
  (void)M; (void)N;
}

// ---------------------------------------------------------------------------
// 64x64-tile GEMM for small/latency-bound shapes. 256 threads, 4x4 microtile.
// Per-element K-accumulation order IDENTICAL (ascending k) -> bitwise-equal.
// NOT safe for in-place C==A row-panels (two blocks share rows): allow64=0.
// ---------------------------------------------------------------------------
template<int OPA, int OPB>
__global__ void __launch_bounds__(256)
gemm64_kernel(int M, int N, int K,
              const float* __restrict__ A, int lda,
              const float* __restrict__ B, int ldb,
              float* __restrict__ C, int ldc,
              float alpha,
              const float* __restrict__ Add, int ldadd, int addI,
              size_t zsA, size_t zsB, size_t zsC, int sym)
{
  if (sym && (int)blockIdx.x > (int)blockIdx.y) return;
  constexpr int PAD = 4;
  A += (size_t)blockIdx.z * zsA;
  B += (size_t)blockIdx.z * zsB;
  C += (size_t)blockIdx.z * zsC;
  __shared__ float As[2][GBK][64 + PAD];
  __shared__ float Bs[2][GBK][64 + PAD];
  const int tid = (int)threadIdx.x;
  const int tx = tid & 15;
  const int ty = tid >> 4;
  const int bm = (int)blockIdx.y * 64;
  const int bn = (int)blockIdx.x * 64;

  const int arow = tid >> 2, aq = tid & 3;    // transpose staging (row-major src)
  const int akk = tid >> 4, amc = tid & 15;   // direct staging

  float4 ra, rb;
  auto loadA = [&](int k0) {
    if (OPA == 0) ra = *reinterpret_cast<const float4*>(&A[(size_t)(bm + arow) * lda + k0 + aq * 4]);
    else          ra = *reinterpret_cast<const float4*>(&A[(size_t)(k0 + akk) * lda + bm + amc * 4]);
  };
  auto storeA = [&](int buf) {
    if (OPA == 0) {
      As[buf][aq * 4 + 0][arow] = ra.x; As[buf][aq * 4 + 1][arow] = ra.y;
      As[buf][aq * 4 + 2][arow] = ra.z; As[buf][aq * 4 + 3][arow] = ra.w;
    } else {
      *reinterpret_cast<float4*>(&As[buf][akk][amc * 4]) = ra;
    }
  };
  auto loadB = [&](int k0) {
    if (OPB == 0) rb = *reinterpret_cast<const float4*>(&B[(size_t)(k0 + akk) * ldb + bn + amc * 4]);
    else          rb = *reinterpret_cast<const float4*>(&B[(size_t)(bn + arow) * ldb + k0 + aq * 4]);
  };
  auto storeB = [&](int buf) {
    if (OPB == 0) {
      *reinterpret_cast<float4*>(&Bs[buf][akk][amc * 4]) = rb;
    } else {
      Bs[buf][aq * 4 + 0][arow] = rb.x; Bs[buf][aq * 4 + 1][arow] = rb.y;
      Bs[buf][aq * 4 + 2][arow] = rb.z; Bs[buf][aq * 4 + 3][arow] = rb.w;
    }
  };

  float acc[4][4];
#pragma unroll
  for (int i = 0; i < 4; ++i)
#pragma unroll
    for (int j = 0; j < 4; ++j) acc[i][j] = 0.f;

  const int nk = K / GBK;
  loadA(0); loadB(0); storeA(0); storeB(0);
  __syncthreads();

  for (int t = 0; t < nk; ++t) {
    const int cur = t & 1;
    if (t + 1 < nk) { loadA((t + 1) * GBK); loadB((t + 1) * GBK); }
#pragma unroll
    for (int kk = 0; kk < GBK; ++kk) {
      float a[4], b[4];
      *reinterpret_cast<float4*>(a) = *reinterpret_cast<const float4*>(&As[cur][kk][ty * 4]);
      *reinterpret_cast<float4*>(b) = *reinterpret_cast<const float4*>(&Bs[cur][kk][tx * 4]);
#pragma unroll
      for (int i = 0; i < 4; ++i)
#pragma unroll
        for (int j = 0; j < 4; ++j)
          acc[i][j] = fmaf(a[i], b[j], acc[i][j]);
    }
    if (t + 1 < nk) { storeA(cur ^ 1); storeB(cur ^ 1); }
    __syncthreads();
  }

#pragma unroll
  for (int i = 0; i < 4; ++i) {
    const int gm = bm + ty * 4 + i;
    const int gn0 = bn + tx * 4;
    float vv[4];
#pragma unroll
    for (int j = 0; j < 4; ++j) vv[j] = alpha * acc[i][j];
    if (Add) {
      const float4 ad = *reinterpret_cast<const float4*>(&Add[(size_t)gm * ldadd + gn0]);
      vv[0] += ad.x; vv[1] += ad.y; vv[2] += ad.z; vv[3] += ad.w;
    }
    if (addI) {
#pragma unroll
      for (int j = 0; j < 4; ++j) if (gm == gn0 + j) vv[j] += 1.f;
    }
    float4 v; v.x = vv[0]; v.y = vv[1]; v.z = vv[2]; v.w = vv[3];
    *reinterpret_cast<float4*>(&C[(size_t)gm * ldc + gn0]) = v;
  }
  (void)M; (void)N;
}

// sum ks partials (compact MxN each) + epilogue
__global__ __launch_bounds__(256)
void reduce_split_kernel(int N, int ldc, float* __restrict__ C,
                         const float* __restrict__ PS, long long MN, int ks,
                         float alpha, const float* __restrict__ Add, int ldadd,
                         int addI, int sym)
{
  long long i4 = ((long long)blockIdx.x * 256 + threadIdx.x) * 4;
  if (i4 >= MN) return;
  const int m = (int)(i4 / N), n = (int)(i4 % N);
  if (sym && (n >> 7) > (m >> 7)) return;
  float4 s = *reinterpret_cast<const float4*>(&PS[i4]);
  for (int z = 1; z < ks; ++z) {
    const float4 p = *reinterpret_cast<const float4*>(&PS[(size_t)z * MN + i4]);
    s.x += p.x; s.y += p.y; s.z += p.z; s.w += p.w;
  }
  float vv[4] = { alpha * s.x, alpha * s.y, alpha * s.z, alpha * s.w };
  if (Add) {
    const float4 ad = *reinterpret_cast<const float4*>(&Add[(size_t)m * ldadd + n]);
    vv[0] += ad.x; vv[1] += ad.y; vv[2] += ad.z; vv[3] += ad.w;
  }
  if (addI) {
#pragma unroll
    for (int j = 0; j < 4; ++j) if (m == n + j) vv[j] += 1.f;
  }
  float4 v; v.x = vv[0]; v.y = vv[1]; v.z = vv[2]; v.w = vv[3];
  *reinterpret_cast<float4*>(&C[(size_t)m * ldc + n]) = v;
}

// mirror lower triangle to upper: C[r][c] = C[c][r] for c > r. Tiled 32x32.
__global__ __launch_bounds__(256)
void mirror_kernel(int n, int ld, float* __restrict__ C)
{
  __shared__ float t[32][33];
  const int bx = (int)blockIdx.x, by = (int)blockIdx.y;
  if (by < bx) return;
  const int r0 = by * 32, c0 = bx * 32;
  const int tx = (int)threadIdx.x & 31, ty4 = ((int)threadIdx.x >> 5) * 4;
#pragma unroll
  for (int k = 0; k < 4; ++k)
    t[ty4 + k][tx] = C[(size_t)(r0 + ty4 + k) * ld + c0 + tx];
  __syncthreads();
  if (by == bx) {
#pragma unroll
    for (int k = 0; k < 4; ++k) {
      int rr = ty4 + k;
      if (tx > rr) C[(size_t)(c0 + rr) * ld + r0 + tx] = t[tx][rr];
    }
  } else {
#pragma unroll
    for (int k = 0; k < 4; ++k)
      C[(size_t)(c0 + ty4 + k) * ld + r0 + tx] = t[tx][ty4 + k];
  }
}

// sym: 0 = full; 1 = lower-only + mirror; 2 = lower-only, upper never read
template<int OPA, int OPB>
static void gemm_launch(hipStream_t st, int M, int N, int K,
                        const float* A, int lda, size_t zsA,
                        const float* B, int ldb, size_t zsB,
                        float* C, int ldc, size_t zsC,
                        float alpha, const float* Add, int ldadd, int addI,
                        int batch, int sym, int allow64)
{
  int ks = 1;
  if (batch == 1 && g_ps_ok && K >= 512) {
    int nbm = M / 128, nbn = N / 128;
    long long blocks = sym ? (long long)nbm * (nbm + 1) / 2 : (long long)nbm * nbn;
    long long MN = (long long)M * N;
    while (ks < 8 && blocks * ks < 512 && (K % (32 * ks)) == 0 && (long long)(ks * 2) * MN <= g_ps_cap)
      ks *= 2;
  }
  if (ks > 1) {
    const int Kp = K / ks;
    const long long MN = (long long)M * N;
    const size_t sA = (OPA == 0) ? (size_t)Kp : (size_t)Kp * lda;
    const size_t sB = (OPB == 0) ? (size_t)Kp * ldb : (size_t)Kp;
    dim3 grid(N / 128, M / 128, ks), blk(256);
    gemm_kernel<OPA, OPB><<<grid, blk, 0, st>>>(M, N, Kp, A, lda, B, ldb,
                                                g_ps, N, 1.f, nullptr, 0, 0, sA, sB, (size_t)MN, sym);
    reduce_split_kernel<<<(int)cdiv((int)(MN / 4), 256), 256, 0, st>>>(
        N, ldc, C, g_ps, MN, ks, alpha, Add, ldadd, addI, sym);
  } else {
    long long blocks128 = (long long)(M / 128) * (N / 128) * batch;
    if (allow64 && (M % 64) == 0 && (N % 64) == 0 && blocks128 < 64) {
      dim3 grid(N / 64, M / 64, batch), blk(256);
      gemm64_kernel<OPA, OPB><<<grid, blk, 0, st>>>(M, N, K, A, lda, B, ldb,
                                                    C, ldc, alpha, Add, ldadd, addI, zsA, zsB, zsC, sym);
    } else {
      dim3 grid(N / 128, M / 128, batch), blk(256);
      gemm_kernel<OPA, OPB><<<grid, blk, 0, st>>>(M, N, K, A, lda, B, ldb,
                                                  C, ldc, alpha, Add, ldadd, addI, zsA, zsB, zsC, sym);
    }
  }
  if (sym == 1) {
    dim3 mg(N / 32, M / 32);
    mirror_kernel<<<mg, 256, 0, st>>>(M, ldc, C);
  }
}

static void gemm_b(hipStream_t st, int opa, int opb, int M, int N, int K,
                   const float* A, int lda, size_t zsA,
                   const float* B, int ldb, size_t zsB,
                   float* C, int ldc, size_t zsC,
                   float alpha, const float* Add, int ldadd, int addI,
                   int batch, int sym = 0, int allow64 = 1)
{
  if (opa == 0 && opb == 0)
    gemm_launch<0,0>(st, M, N, K, A, lda, zsA, B, ldb, zsB, C, ldc, zsC, alpha, Add, ldadd, addI, batch, sym, allow64);
  else if (opa == 0 && opb == 1)
    gemm_launch<0,1>(st, M, N, K, A, lda, zsA, B, ldb, zsB, C, ldc, zsC, alpha, Add, ldadd, addI, batch, sym, allow64);
  else
    gemm_launch<1,0>(st, M, N, K, A, lda, zsA, B, ldb, zsB, C, ldc, zsC, alpha, Add, ldadd, addI, batch, sym, allow64);
}

static void gemm(hipStream_t st, int opa, int opb, int M, int N, int K,
                 const float* A, int lda, const float* B, int ldb,
                 float* C, int ldc, float alpha,
                 const float* Add, int ldadd, int addI, int sym = 0, int allow64 = 1)
{
  gemm_b(st, opa, opb, M, N, K, A, lda, 0, B, ldb, 0, C, ldc, 0, alpha, Add, ldadd, addI, 1, sym, allow64);
}

// ---------------------------------------------------------------------------
// Matvec helpers
// ---------------------------------------------------------------------------
__global__ __launch_bounds__(256)
void mv_n_kernel(int M, int K, const float* A, int lda, const float* x, float* y)
{
  int m = (int)blockIdx.x;
  if (m >= M) return;
  const float* row = A + (size_t)m * lda;
  float s = 0.f;
  for (int k = (int)threadIdx.x; k < K; k += 256) s += row[k] * x[k];
  __shared__ float red[256];
  red[threadIdx.x] = s;
  __syncthreads();
  for (int off = 128; off > 0; off >>= 1) {
    if ((int)threadIdx.x < off) red[threadIdx.x] += red[threadIdx.x + off];
    __syncthreads();
  }
  if (threadIdx.x == 0) y[m] = red[0];
}

// ---- column matvec (w = A^T x), two-stage row-split ----
__global__ __launch_bounds__(256)
void mv_t3_part_kernel(int Nrows, int Ncols, const float* __restrict__ A, int lda,
                       const float* __restrict__ x0, const float* __restrict__ x1,
                       const float* __restrict__ x2, float* __restrict__ PS, int RS)
{
  int e = (int)(blockIdx.x * 256 + threadIdx.x);
  if (e >= Ncols) return;
  int chunk = cdiv(Nrows, RS);
  int rs = (int)blockIdx.y;
  int n0 = rs * chunk, n1 = min(Nrows, n0 + chunk);
  float s0 = 0.f, s1 = 0.f, s2 = 0.f;
  for (int n = n0; n < n1; ++n) {
    float b = A[(size_t)n * lda + e];
    s0 += b * x0[n]; s1 += b * x1[n]; s2 += b * x2[n];
  }
  PS[((size_t)rs * 3 + 0) * Ncols + e] = s0;
  PS[((size_t)rs * 3 + 1) * Ncols + e] = s1;
  PS[((size_t)rs * 3 + 2) * Ncols + e] = s2;
}

__global__ __launch_bounds__(256)
void mv_t3_red_kernel(int Ncols, const float* __restrict__ PS, int RS,
                      float* w0, float* w1, float* w2)
{
  int e = (int)(blockIdx.x * 256 + threadIdx.x);
  if (e >= Ncols) return;
  float s0 = 0.f, s1 = 0.f, s2 = 0.f;
  for (int rs = 0; rs < RS; ++rs) {
    s0 += PS[((size_t)rs * 3 + 0) * Ncols + e];
    s1 += PS[((size_t)rs * 3 + 1) * Ncols + e];
    s2 += PS[((size_t)rs * 3 + 2) * Ncols + e];
  }
  w0[e] = s0; w1[e] = s1; w2[e] = s2;
}

__global__ __launch_bounds__(256)
void mv_t_part_kernel(int Nrows, int Ncols, const float* __restrict__ A, int lda,
                      const float* __restrict__ x, float* __restrict__ PS, int RS)
{
  int e = (int)(blockIdx.x * 256 + threadIdx.x);
  if (e >= Ncols) return;
  int chunk = cdiv(Nrows, RS);
  int rs = (int)blockIdx.y;
  int n0 = rs * chunk, n1 = min(Nrows, n0 + chunk);
  float s = 0.f;
  for (int n = n0; n < n1; ++n) s += A[(size_t)n * lda + e] * x[n];
  PS[(size_t)rs * Ncols + e] = s;
}

__global__ __launch_bounds__(256)
void mv_t_red_kernel(int Ncols, const float* __restrict__ PS, int RS,
                     const float* __restrict__ addv, float* w)
{
  int e = (int)(blockIdx.x * 256 + threadIdx.x);
  if (e >= Ncols) return;
  float s = 0.f;
  for (int rs = 0; rs < RS; ++rs) s += PS[(size_t)rs * Ncols + e];
  if (addv) s += addv[e];
  w[e] = s;
}

// single-stage fallbacks
__global__ __launch_bounds__(256)
void mv_t_kernel(int Nrows, int Ncols, const float* A, int lda,
                 const float* x, const float* addv, float* w)
{
  int e = (int)(blockIdx.x * blockDim.x + threadIdx.x);
  if (e >= Ncols) return;
  float s = 0.f;
  for (int n = 0; n < Nrows; ++n) s += A[(size_t)n * lda + e] * x[n];
  if (addv) s += addv[e];
  w[e] = s;
}

__global__ __launch_bounds__(256)
void mv_t3_kernel(int Nrows, int Ncols, const float* A, int lda,
                  const float* x0, const float* x1, const float* x2,
                  float* w0, float* w1, float* w2)
{
  int e = (int)(blockIdx.x * blockDim.x + threadIdx.x);
  if (e >= Ncols) return;
  float s0 = 0.f, s1 = 0.f, s2 = 0.f;
  for (int n = 0; n < Nrows; ++n) {
    float b = A[(size_t)n * lda + e];
    s0 += b * x0[n]; s1 += b * x1[n]; s2 += b * x2[n];
  }
  w0[e] = s0; w1[e] = s1; w2[e] = s2;
}

static void mv_t3(hipStream_t st, int Nrows, int Ncols, const float* A, int lda,
                  const float* x0, const float* x1, const float* x2,
                  float* w0, float* w1, float* w2)
{
  const int RS = 64;
  if (g_ps_ok && (long long)RS * 3 * Ncols <= g_ps_cap) {
    dim3 grid(cdiv(Ncols, 256), RS);
    mv_t3_part_kernel<<<grid, 256, 0, st>>>(Nrows, Ncols, A, lda, x0, x1, x2, g_ps, RS);
    mv_t3_red_kernel<<<cdiv(Ncols, 256), 256, 0, st>>>(Ncols, g_ps, RS, w0, w1, w2);
  } else {
    mv_t3_kernel<<<cdiv(Ncols, 256), 256, 0, st>>>(Nrows, Ncols, A, lda, x0, x1, x2, w0, w1, w2);
  }
}

static void mv_t_add(hipStream_t st, int Nrows, int Ncols, const float* A, int lda,
                     const float* x, const float* addv, float* w)
{
  const int RS = 64;
  if (g_ps_ok && (long long)RS * Ncols <= g_ps_cap) {
    dim3 grid(cdiv(Ncols, 256), RS);
    mv_t_part_kernel<<<grid, 256, 0, st>>>(Nrows, Ncols, A, lda, x, g_ps, RS);
    mv_t_red_kernel<<<cdiv(Ncols, 256), 256, 0, st>>>(Ncols, g_ps, RS, addv, w);
  } else {
    mv_t_kernel<<<cdiv(Ncols, 256), 256, 0, st>>>(Nrows, Ncols, A, lda, x, addv, w);
  }
}

// ---------------------------------------------------------------------------
// elementwise helpers
// ---------------------------------------------------------------------------
__global__ __launch_bounds__(256)
void scale_cols_kernel(long long total, int E, const float* B, const float* sv, float* out)
{
  long long i = (long long)blockIdx.x * blockDim.x + threadIdx.x;
  if (i < total) {
    int e = (int)(i % E);
    out[i] = B[i] * sv[e];
  }
}

__global__ __launch_bounds__(256)
void build_h_kernel(long long total, int E,
                    const float* B, const float* LB, const float* L2B,
                    const float* w0, const float* w1, const float* w2,
                    const float* a, float* H)
{
  long long i = (long long)blockIdx.x * blockDim.x + threadIdx.x;
  if (i < total) {
    int e = (int)(i % E);
    float a1 = a[1], a2 = a[2], a3 = a[3];
    float b = B[i], lb = LB[i], l2b = L2B[i];
    H[i] = w0[e] * (a1 * b + a2 * lb + a3 * l2b)
         + w1[e] * (a2 * b + a3 * lb)
         + w2[e] * (a3 * b);
  }
}

__global__ __launch_bounds__(256)
void poly_resid_kernel(int Nn, const float* a, const float* q,
                       const float* c1, const float* c2, const float* c3,
                       const float* y, float* resid)
{
  int n = (int)(blockIdx.x * blockDim.x + threadIdx.x);
  if (n < Nn)
    resid[n] = y[n] - (a[0] * q[n] + a[1] * c1[n] + a[2] * c2[n] + a[3] * c3[n]);
}

__global__ __launch_bounds__(256)
void fzero_kernel(float* p, long long n)
{
  long long i = (long long)blockIdx.x * blockDim.x + threadIdx.x;
  if (i < n) p[i] = 0.f;
}

// ---------------------------------------------------------------------------
// fused index setup (single block)
// ---------------------------------------------------------------------------
__global__ __launch_bounds__(1024)
void setup_idx_kernel(const void* __restrict__ connRaw, int Kc, int E,
                      const float* __restrict__ s_upd,
                      int* conn32, int* invc, float* s2, float* outS)
{
  const int tid = (int)threadIdx.x;
  const unsigned* u = (const unsigned*)connRaw;
  const bool is64 = (u[1] | u[3] | u[5] | u[7]) == 0u;
  for (int i = tid; i < Kc; i += 1024)
    conn32[i] = is64 ? (int)((const long long*)connRaw)[i] : ((const int*)connRaw)[i];
  for (int e = tid; e < E; e += 1024) invc[e] = -1;
  __syncthreads();
  for (int i = tid; i < Kc; i += 1024) invc[conn32[i]] = i;
  __syncthreads();
  for (int e = tid; e < E; e += 1024) {
    float v = (invc[e] >= 0) ? s_upd[e] : 0.f;
    s2[e] = v;
    outS[e] = v;
  }
}

// fused gather of H2 (Nn x Kc) and Scc (Kc x Kc)
__global__ __launch_bounds__(256)
void gather2_kernel(int Nn, int Kc, int E,
                    const float* __restrict__ H2full, const float* __restrict__ Sig,
                    const int* __restrict__ conn, float* H2, float* Scc)
{
  const long long NK = (long long)Nn * Kc;
  const long long KK = (long long)Kc * Kc;
  long long i = (long long)blockIdx.x * blockDim.x + threadIdx.x;
  if (i < NK) {
    int n = (int)(i / Kc), c = (int)(i % Kc);
    H2[i] = H2full[(size_t)n * E + conn[c]];
  } else if (i < NK + KK) {
    long long j = i - NK;
    int r = (int)(j / Kc), c = (int)(j % Kc);
    Scc[j] = Sig[(size_t)conn[r] * E + conn[c]];
  }
}

__global__ __launch_bounds__(256)
void write_sigma_out_kernel(long long total, int E, const float* Small, int Kc,
                            const int* inv, float* out)
{
  long long i = (long long)blockIdx.x * blockDim.x + threadIdx.x;
  if (i < total) {
    int r = (int)(i / E), c = (int)(i % E);
    int ir = inv[r], ic = inv[c];
    out[i] = (ir >= 0 && ic >= 0) ? Small[(size_t)ir * Kc + ic] : 0.f;
  }
}

// ---------------------------------------------------------------------------
// Fused Cholesky leaf (1024 threads): factor 128x128 diag block AND invert it.
// 8-wide panels; wave-synchronous factor panel; rank-8 trailing updates.
// Writes ONLY invL (to Linv at (off,off)).
// ---------------------------------------------------------------------------
__global__ __launch_bounds__(1024)
void chol_leaf_kernel(const float* __restrict__ S, int lda, int off,
                      float* __restrict__ Linv, int ldi)
{
  __shared__ float T[128][132];
  __shared__ float X[128][132];
  const int tid = (int)threadIdx.x;
  const float* Ab = S + (size_t)off * lda + off;
  for (int idx = tid; idx < 128 * 32; idx += 1024) {
    int r = idx >> 5, c4 = (idx & 31) << 2;
    const float4 v = *reinterpret_cast<const float4*>(&Ab[(size_t)r * lda + c4]);
    *reinterpret_cast<float4*>(&T[r][c4]) = v;
    X[r][c4 + 0] = (r == c4 + 0) ? 1.f : 0.f;
    X[r][c4 + 1] = (r == c4 + 1) ? 1.f : 0.f;
    X[r][c4 + 2] = (r == c4 + 2) ? 1.f : 0.f;
    X[r][c4 + 3] = (r == c4 + 3) ? 1.f : 0.f;
  }
  __syncthreads();
  const int wave = tid >> 6;
  const int lane = tid & 63;
  const int g32 = tid >> 5, l32 = tid & 31;

  for (int j0 = 0; j0 < 128; j0 += 8) {
    if (wave == 0) {
      for (int t = 0; t < 8; ++t) {
        const int j = j0 + t;
#pragma unroll
        for (int rr = 0; rr < 2; ++rr) {
          const int r = lane + 64 * rr;
          if (r >= j) {
            float s = T[r][j];
            for (int u = 0; u < t; ++u) s -= T[r][j0 + u] * T[j][j0 + u];
            T[r][j] = s;
          }
        }
        const float d = sqrtf(T[j][j]);
        const float inv = 1.f / d;
#pragma unroll
        for (int rr = 0; rr < 2; ++rr) {
          const int r = lane + 64 * rr;
          if (r > j) T[r][j] *= inv;
          else if (r == j) T[j][j] = d;
        }
      }
    }
    __syncthreads();
    for (int r = j0 + 8 + g32; r < 128; r += 32) {
      const float4 a0 = *reinterpret_cast<const float4*>(&T[r][j0]);
      const float4 a1 = *reinterpret_cast<const float4*>(&T[r][j0 + 4]);
      for (int c = j0 + 8 + l32; c <= r; c += 32) {
        const float4 b0 = *reinterpret_cast<const float4*>(&T[c][j0]);
        const float4 b1 = *reinterpret_cast<const float4*>(&T[c][j0 + 4]);
        T[r][c] -= a0.x * b0.x + a0.y * b0.y + a0.z * b0.z + a0.w * b0.w
                 + a1.x * b1.x + a1.y * b1.y + a1.z * b1.z + a1.w * b1.w;
      }
    }
    __syncthreads();
  }

  for (int j0 = 0; j0 < 128; j0 += 8) {
    if (tid < 128) {
      const int c = tid;
      float xp[8];
#pragma unroll
      for (int t = 0; t < 8; ++t) {
        const int j = j0 + t;
        if (c <= j) {
          float s = X[j][c];
          for (int u = 0; u < t; ++u) s -= T[j][j0 + u] * xp[u];
          xp[t] = s / T[j][j];
          X[j][c] = xp[t];
        } else {
          xp[t] = 0.f;
        }
      }
    }
    __syncthreads();
    for (int i = j0 + 8 + g32; i < 128; i += 32) {
      const float4 a0 = *reinterpret_cast<const float4*>(&T[i][j0]);
      const float4 a1 = *reinterpret_cast<const float4*>(&T[i][j0 + 4]);
      for (int c = l32; c <= j0 + 7; c += 32) {
        X[i][c] -= a0.x * X[j0][c]     + a0.y * X[j0 + 1][c]
                 + a0.z * X[j0 + 2][c] + a0.w * X[j0 + 3][c]
                 + a1.x * X[j0 + 4][c] + a1.y * X[j0 + 5][c]
                 + a1.z * X[j0 + 6][c] + a1.w * X[j0 + 7][c];
      }
    }
    __syncthreads();
  }

  float* Ob = Linv + (size_t)off * ldi + off;
  for (int idx = tid; idx < 128 * 32; idx += 1024) {
    int r = idx >> 5, c4 = (idx & 31) << 2;
    float4 v;
    v.x = X[r][c4]; v.y = X[r][c4 + 1]; v.z = X[r][c4 + 2]; v.w = X[r][c4 + 3];
    *reinterpret_cast<float4*>(&Ob[(size_t)r * ldi + c4]) = v;
  }
}

// ---------------------------------------------------------------------------
// SPD inverse: S (n x n, lower valid) -> Sinv (full). S destroyed.
// ---------------------------------------------------------------------------
static void spd_inverse(hipStream_t st, float* S, float* Linv, float* Sinv, float* TT, int n)
{
  long long nn = (long long)n * n;
  fzero_kernel<<<cdiv((int)nn, 256), 256, 0, st>>>(Linv, nn);
  for (int off = 0; off < n; off += 128) {
    chol_leaf_kernel<<<1, 1024, 0, st>>>(S, n, off, Linv, n);
    int mrem = n - off - 128;
    if (mrem > 0) {
      float* P = S + (size_t)(off + 128) * n + off;
      // in-place TRSM-apply: must stay 128-tile (64-tile would race on shared rows)
      gemm(st, 0, 1, mrem, 128, 128, P, n, Linv + (size_t)off * (n + 1), n, P, n, 1.f, nullptr, 0, 0, 0, 0);
      float* Ct = S + (size_t)(off + 128) * (n + 1);
      gemm(st, 0, 1, mrem, mrem, 128, P, n, P, n, Ct, n, -1.f, Ct, n, 0, 2);  // SYRK, lower only
    }
  }
  for (int m = 128; m < n; m <<= 1) {
    int pairs = n / (2 * m);
    size_t zs = (size_t)2 * m * (n + 1);
    gemm_b(st, 0, 0, m, m, m, S + (size_t)m * n, n, zs, Linv, n, zs,
           TT, m, (size_t)m * m, 1.f, nullptr, 0, 0, pairs, 0);
    gemm_b(st, 0, 0, m, m, m, Linv + (size_t)m * (n + 1), n, zs, TT, m, (size_t)m * m,
           Linv + (size_t)m * n, n, zs, -1.f, nullptr, 0, 0, pairs, 0);
  }
  gemm(st, 1, 0, n, n, n, Linv, n, Linv, n, Sinv, n, 1.f, nullptr, 0, 0, 1);  // sym + mirror
}

// ---------------------------------------------------------------------------
extern "C" void kernel_launch(void* const* d_in, const int* in_sizes, int n_in,
                              void* d_out, int out_size, void* d_ws, size_t ws_size,
                              hipStream_t stream)
{
  const float* F  = (const float*)d_in[0];
  const float* B  = (const float*)d_in[1];
  const float* V  = (const float*)d_in[2];
  const float* W  = (const float*)d_in[3];
  const float* Sg = (const float*)d_in[4];
  const float* sv = (const float*)d_in[5];
  const float* av = (const float*)d_in[6];
  const float* q  = (const float*)d_in[7];
  const float* y  = (const float*)d_in[8];
  const void*  connRaw = d_in[10];

  const int E  = in_sizes[5];
  const int Nn = in_sizes[7];
  const int Kc = in_sizes[10];

  const size_t EE = (size_t)E * E;
  const size_t NE = (size_t)Nn * E;
  const size_t NN = (size_t)Nn * Nn;
  const size_t NK = (size_t)Nn * Kc;
  const size_t KK = (size_t)Kc * Kc;

  float* ws = (float*)d_ws;
  float* EE_A = ws;
  float* EE_B = EE_A + EE;
  float* NE_1 = EE_B + EE;
  float* NE_2 = NE_1 + NE;   // Y / TT / U / T10 (time-disjoint)
  float* NE_3 = NE_2 + NE;
  float* NN_1 = NE_3 + NE;   // L / S factor
  float* NN_2 = NN_1 + NN;   // Linv
  float* NN_3 = NN_2 + NN;   // Sinv
  float* vec  = NN_3 + NN;
  float* s1    = vec;            vec += E;
  float* c1    = vec;            vec += Nn;
  float* c2    = vec;            vec += Nn;
  float* c3    = vec;            vec += Nn;
  float* w0    = vec;            vec += E;
  float* w1    = vec;            vec += E;
  float* w2    = vec;            vec += E;
  float* resid = vec;            vec += Nn;
  float* s_upd = vec;            vec += E;
  float* s2    = vec;            vec += E;
  int* conn32  = (int*)vec;
  int* invc    = conn32 + Kc;
  float* after_ints = (float*)(invc + E);

  // shared scratch (split-K partials + matvec partials), gated on ws_size
  uintptr_t psa = ((uintptr_t)after_ints + 255) & ~(uintptr_t)255;
  g_ps = (float*)psa;
  g_ps_ok = 0;
  for (long long capf = 4 * (long long)EE; capf >= 2 * (long long)EE; capf /= 2) {
    size_t need = (size_t)((char*)(g_ps + capf) - (char*)d_ws);
    if (need <= ws_size) { g_ps_cap = capf; g_ps_ok = 1; break; }
  }

  float* outS   = (float*)d_out;   // E
  float* outSig = outS + E;        // E*E; scratch until final write
  float* EE_C   = outSig;
  float* TT     = NE_2;            // bisection temp (dead region at that time)

  const long long totNE = (long long)Nn * E;
  const long long totEE = (long long)E * E;

  // ---- stage 1 ----
  mv_n_kernel<<<E, 256, 0, stream>>>(E, E, F, E, sv, s1);                        // s1 = F s
  gemm(stream, 0, 0, E, E, E, F, E, Sg, E, EE_A, E, 1.f, nullptr, 0, 0, 0);      // G1 = F Sigma
  gemm(stream, 0, 1, E, E, E, EE_A, E, F, E, EE_B, E, 1.f, V, E, 0, 1);          // Sigma1 = G1 F^T + V (sym)
  scale_cols_kernel<<<cdiv((int)totNE, 256), 256, 0, stream>>>(totNE, E, B, s1, NE_1); // Bs
  gemm(stream, 0, 1, Nn, Nn, E, NE_1, E, B, E, NN_1, Nn, 1.f, nullptr, 0, 0, 1); // L = Bs B^T (sym+mirror)
  mv_n_kernel<<<Nn, 256, 0, stream>>>(Nn, Nn, NN_1, Nn, q, c1);
  mv_n_kernel<<<Nn, 256, 0, stream>>>(Nn, Nn, NN_1, Nn, c1, c2);
  mv_n_kernel<<<Nn, 256, 0, stream>>>(Nn, Nn, NN_1, Nn, c2, c3);
  mv_t3(stream, Nn, E, B, E, q, c1, c2, w0, w1, w2);
  poly_resid_kernel<<<cdiv(Nn, 256), 256, 0, stream>>>(Nn, av, q, c1, c2, c3, y, resid);
  gemm(stream, 0, 0, Nn, E, Nn, NN_1, Nn, B, E, NE_1, E, 1.f, nullptr, 0, 0, 0); // LB
  gemm(stream, 0, 0, Nn, E, Nn, NN_1, Nn, NE_1, E, NE_2, E, 1.f, nullptr, 0, 0, 0); // L2B
  build_h_kernel<<<cdiv((int)totNE, 256), 256, 0, stream>>>(totNE, E, B, NE_1, NE_2, w0, w1, w2, av, NE_3); // H
  gemm(stream, 0, 0, Nn, E, E, NE_3, E, EE_B, E, NE_1, E, 1.f, nullptr, 0, 0, 0);// T2 = H Sigma1
  gemm(stream, 0, 1, Nn, Nn, E, NE_1, E, NE_3, E, NN_1, Nn, 1.f, W, Nn, 0, 2);   // S = T2 H^T + W (lower only)
  spd_inverse(stream, NN_1, NN_2, NN_3, TT, Nn);                                 // Sinv in NN_3
  gemm(stream, 0, 0, Nn, E, Nn, NN_3, Nn, NE_1, E, NE_2, E, 1.f, nullptr, 0, 0, 0); // Y = Sinv T2
  mv_t_add(stream, Nn, E, NE_2, E, resid, s1, s_upd);                            // s_upd = s1 + Y^T resid
  // Joseph form without forming ImKH (K = Y^T):
  gemm(stream, 1, 0, E, E, Nn, NE_2, E, NE_1, E, EE_A, E, -1.f, EE_B, E, 0, 0);  // T3 = Sigma1 - Y^T T2
  gemm(stream, 0, 1, E, Nn, E, EE_A, E, NE_3, E, NE_1, Nn, 1.f, nullptr, 0, 0, 0); // U = T3 H^T
  gemm(stream, 0, 0, E, E, Nn, NE_1, Nn, NE_2, E, EE_C, E, -1.f, EE_A, E, 0, 1); // T4 = T3 - U Y (sym)
  gemm(stream, 1, 0, E, Nn, Nn, NE_2, E, W, Nn, NE_1, Nn, 1.f, nullptr, 0, 0, 0);// T5 = Y^T W
  gemm(stream, 0, 0, E, E, Nn, NE_1, Nn, NE_2, E, EE_B, E, 1.f, EE_C, E, 0, 1);  // Sigma2 = T5 Y + T4 (sym)

  // ---- masking / stage 2 ----
  setup_idx_kernel<<<1, 1024, 0, stream>>>(connRaw, Kc, E, s_upd, conn32, invc, s2, outS);

  scale_cols_kernel<<<cdiv((int)totNE, 256), 256, 0, stream>>>(totNE, E, B, s2, NE_1); // Bs2
  gemm(stream, 0, 1, Nn, Nn, E, NE_1, E, B, E, NN_1, Nn, 1.f, nullptr, 0, 0, 1); // L2 (sym+mirror)
  mv_n_kernel<<<Nn, 256, 0, stream>>>(Nn, Nn, NN_1, Nn, q, c1);
  mv_n_kernel<<<Nn, 256, 0, stream>>>(Nn, Nn, NN_1, Nn, c1, c2);
  mv_t3(stream, Nn, E, B, E, q, c1, c2, w0, w1, w2);
  gemm(stream, 0, 0, Nn, E, Nn, NN_1, Nn, B, E, NE_1, E, 1.f, nullptr, 0, 0, 0); // L2 B
  gemm(stream, 0, 0, Nn, E, Nn, NN_1, Nn, NE_1, E, NE_2, E, 1.f, nullptr, 0, 0, 0); // L2^2 B
  build_h_kernel<<<cdiv((int)totNE, 256), 256, 0, stream>>>(totNE, E, B, NE_1, NE_2, w0, w1, w2, av, NE_3); // H2full
  gather2_kernel<<<cdiv((int)(NK + KK), 256), 256, 0, stream>>>(Nn, Kc, E, NE_3, EE_B, conn32, EE_A, EE_A + NK); // H2, Scc
  gemm(stream, 0, 0, Nn, Kc, Kc, EE_A, Kc, EE_A + NK, Kc, EE_B, Kc, 1.f, nullptr, 0, 0, 0); // T7 = H2 Scc
  gemm(stream, 0, 1, Nn, Nn, Kc, EE_B, Kc, EE_A, Kc, NN_1, Nn, 1.f, W, Nn, 0, 2);// S2 = T7 H2^T + W (lower only)
  spd_inverse(stream, NN_1, NN_2, NN_3, TT, Nn);                                 // Sinv2 in NN_3
  gemm(stream, 0, 0, Nn, Kc, Nn, NN_3, Nn, EE_B, Kc, NE_1, Kc, 1.f, nullptr, 0, 0, 0);  // Y2 = Sinv2 T7
  gemm(stream, 1, 0, Kc, Kc, Nn, NE_1, Kc, EE_A, Kc, EE_C, Kc, -1.f, nullptr, 0, 1, 0); // ImKH2 = I - Y2^T H2
  gemm(stream, 0, 0, Kc, Kc, Kc, EE_C, Kc, EE_A + NK, Kc, EE_C + KK, Kc, 1.f, nullptr, 0, 0, 0); // T8 = ImKH2 Scc
  gemm(stream, 0, 1, Kc, Kc, Kc, EE_C + KK, Kc, EE_C, Kc, EE_A + NK, Kc, 1.f, nullptr, 0, 0, 1); // T9 (sym)
  gemm(stream, 1, 0, Kc, Nn, Nn, NE_1, Kc, W, Nn, NE_2, Nn, 1.f, nullptr, 0, 0, 0); // T10 = Y2^T W
  gemm(stream, 0, 0, Kc, Kc, Nn, NE_2, Nn, NE_1, Kc, EE_A + NK, Kc, 1.f, EE_A + NK, Kc, 0, 1); // Small (sym)

  write_sigma_out_kernel<<<cdiv((int)totEE, 256), 256, 0, stream>>>(totEE, E, EE_A + NK, Kc, invc, outSig);

  (void)n_in; (void)out_size; (void)ws_size;
}

// Round 15
// 4071.121 us; speedup vs baseline: 4.7116x; 4.7116x over previous
//
#include <hip/hip_runtime.h>

__host__ __device__ static inline int cdiv(int a, int b) { return (a + b - 1) / b; }

#define GBK 16

// split-K / matvec-partial workspace (set per kernel_launch; deterministic)
static float* g_ps = nullptr;
static long long g_ps_cap = 0;   // capacity in floats
static int g_ps_ok = 0;

// ---------------------------------------------------------------------------
// GEMM: C = alpha * opA(A) opB(B) + (Add?Add:0) + (addI?I:0)
// OPA==0: A is MxK row-major.  OPA==1: A physical KxM; opA[m,k]=A[k*lda+m]
// OPB==0: B is KxN row-major.  OPB==1: B physical NxK; opB[k,n]=B[n*ldb+k]
// sym!=0: skip blocks with col-block > row-block.
// 128x128 tile, 512 threads, 4x8 microtile, double-buffered LDS. 124 VGPR ->
// 4 waves/SIMD allowed; at this config the kernel sits at the ds_read
// throughput ceiling (~70 TF). 8x8 microtile closed: 2w/SIMD starves (r7),
// 3w/SIMD cap spills acc to scratch (r14).
// REQUIRES: M,N multiples of 128; K multiple of 16; 16B-aligned pointers.
// ---------------------------------------------------------------------------
template<int OPA, int OPB>
__global__ void __launch_bounds__(512)
gemm_kernel(int M, int N, int K,
            const float* __restrict__ A, int lda,
            const float* __restrict__ B, int ldb,
            float* __restrict__ C, int ldc,
            float alpha,
            const float* __restrict__ Add, int ldadd, int addI,
            size_t zsA, size_t zsB, size_t zsC, int sym)
{
  if (sym && (int)blockIdx.x > (int)blockIdx.y) return;
  constexpr int TMp = 128, TNp = 128, PAD = 4;
  A += (size_t)blockIdx.z * zsA;
  B += (size_t)blockIdx.z * zsB;
  C += (size_t)blockIdx.z * zsC;
  __shared__ float As[2][GBK][TMp + PAD];
  __shared__ float Bs[2][GBK][TNp + PAD];
  const int tid = (int)threadIdx.x;
  const int tx = tid & 15;
  const int ty = tid >> 4;
  const int bm = (int)blockIdx.y * TMp;
  const int bn = (int)blockIdx.x * TNp;

  const int arow = tid >> 2, aq = tid & 3;   // transpose staging path
  const int akk = tid >> 5, amc = tid & 31;  // direct staging path

  float4 ra, rb;
  auto loadA = [&](int k0) {
    if (OPA == 0) ra = *reinterpret_cast<const float4*>(&A[(size_t)(bm + arow) * lda + k0 + aq * 4]);
    else          ra = *reinterpret_cast<const float4*>(&A[(size_t)(k0 + akk) * lda + bm + amc * 4]);
  };
  auto storeA = [&](int buf) {
    if (OPA == 0) {
      As[buf][aq * 4 + 0][arow] = ra.x; As[buf][aq * 4 + 1][arow] = ra.y;
      As[buf][aq * 4 + 2][arow] = ra.z; As[buf][aq * 4 + 3][arow] = ra.w;
    } else {
      *reinterpret_cast<float4*>(&As[buf][akk][amc * 4]) = ra;
    }
  };
  auto loadB = [&](int k0) {
    if (OPB == 0) rb = *reinterpret_cast<const float4*>(&B[(size_t)(k0 + akk) * ldb + bn + amc * 4]);
    else          rb = *reinterpret_cast<const float4*>(&B[(size_t)(bn + arow) * ldb + k0 + aq * 4]);
  };
  auto storeB = [&](int buf) {
    if (OPB == 0) {
      *reinterpret_cast<float4*>(&Bs[buf][akk][amc * 4]) = rb;
    } else {
      Bs[buf][aq * 4 + 0][arow] = rb.x; Bs[buf][aq * 4 + 1][arow] = rb.y;
      Bs[buf][aq * 4 + 2][arow] = rb.z; Bs[buf][aq * 4 + 3][arow] = rb.w;
    }
  };

  float acc[4][8];
#pragma unroll
  for (int i = 0; i < 4; ++i)
#pragma unroll
    for (int j = 0; j < 8; ++j) acc[i][j] = 0.f;

  const int nk = K / GBK;
  loadA(0); loadB(0); storeA(0); storeB(0);
  __syncthreads();

  for (int t = 0; t < nk; ++t) {
    const int cur = t & 1;
    if (t + 1 < nk) { loadA((t + 1) * GBK); loadB((t + 1) * GBK); }
#pragma unroll
    for (int kk = 0; kk < GBK; ++kk) {
      float a[4], b[8];
      *reinterpret_cast<float4*>(a) = *reinterpret_cast<const float4*>(&As[cur][kk][ty * 4]);
      *reinterpret_cast<float4*>(&b[0]) = *reinterpret_cast<const float4*>(&Bs[cur][kk][tx * 4]);
      *reinterpret_cast<float4*>(&b[4]) = *reinterpret_cast<const float4*>(&Bs[cur][kk][64 + tx * 4]);
#pragma unroll
      for (int i = 0; i < 4; ++i)
#pragma unroll
        for (int j = 0; j < 8; ++j)
          acc[i][j] = fmaf(a[i], b[j], acc[i][j]);
    }
    if (t + 1 < nk) { storeA(cur ^ 1); storeB(cur ^ 1); }
    __syncthreads();
  }

#pragma unroll
  for (int i = 0; i < 4; ++i) {
    const int gm = bm + ty * 4 + i;
#pragma unroll
    for (int g = 0; g < 2; ++g) {
      const int gn0 = bn + g * 64 + tx * 4;
      float vv[4];
#pragma unroll
      for (int j = 0; j < 4; ++j) vv[j] = alpha * acc[i][g * 4 + j];
      if (Add) {
        const float4 ad = *reinterpret_cast<const float4*>(&Add[(size_t)gm * ldadd + gn0]);
        vv[0] += ad.x; vv[1] += ad.y; vv[2] += ad.z; vv[3] += ad.w;
      }
      if (addI) {
#pragma unroll
        for (int j = 0; j < 4; ++j) if (gm == gn0 + j) vv[j] += 1.f;
      }
      float4 v; v.x = vv[0]; v.y = vv[1]; v.z = vv[2]; v.w = vv[3];
      *reinterpret_cast<float4*>(&C[(size_t)gm * ldc + gn0]) = v;
    }
  }
  (void)M; (void)N;
}

// ---------------------------------------------------------------------------
// 64x64-tile GEMM for small/latency-bound shapes. 256 threads, 4x4 microtile.
// Per-element K-accumulation order IDENTICAL (ascending k) -> bitwise-equal.
// NOT safe for in-place C==A row-panels (two blocks share rows): allow64=0.
// ---------------------------------------------------------------------------
template<int OPA, int OPB>
__global__ void __launch_bounds__(256)
gemm64_kernel(int M, int N, int K,
              const float* __restrict__ A, int lda,
              const float* __restrict__ B, int ldb,
              float* __restrict__ C, int ldc,
              float alpha,
              const float* __restrict__ Add, int ldadd, int addI,
              size_t zsA, size_t zsB, size_t zsC, int sym)
{
  if (sym && (int)blockIdx.x > (int)blockIdx.y) return;
  constexpr int PAD = 4;
  A += (size_t)blockIdx.z * zsA;
  B += (size_t)blockIdx.z * zsB;
  C += (size_t)blockIdx.z * zsC;
  __shared__ float As[2][GBK][64 + PAD];
  __shared__ float Bs[2][GBK][64 + PAD];
  const int tid = (int)threadIdx.x;
  const int tx = tid & 15;
  const int ty = tid >> 4;
  const int bm = (int)blockIdx.y * 64;
  const int bn = (int)blockIdx.x * 64;

  const int arow = tid >> 2, aq = tid & 3;    // transpose staging (row-major src)
  const int akk = tid >> 4, amc = tid & 15;   // direct staging

  float4 ra, rb;
  auto loadA = [&](int k0) {
    if (OPA == 0) ra = *reinterpret_cast<const float4*>(&A[(size_t)(bm + arow) * lda + k0 + aq * 4]);
    else          ra = *reinterpret_cast<const float4*>(&A[(size_t)(k0 + akk) * lda + bm + amc * 4]);
  };
  auto storeA = [&](int buf) {
    if (OPA == 0) {
      As[buf][aq * 4 + 0][arow] = ra.x; As[buf][aq * 4 + 1][arow] = ra.y;
      As[buf][aq * 4 + 2][arow] = ra.z; As[buf][aq * 4 + 3][arow] = ra.w;
    } else {
      *reinterpret_cast<float4*>(&As[buf][akk][amc * 4]) = ra;
    }
  };
  auto loadB = [&](int k0) {
    if (OPB == 0) rb = *reinterpret_cast<const float4*>(&B[(size_t)(k0 + akk) * ldb + bn + amc * 4]);
    else          rb = *reinterpret_cast<const float4*>(&B[(size_t)(bn + arow) * ldb + k0 + aq * 4]);
  };
  auto storeB = [&](int buf) {
    if (OPB == 0) {
      *reinterpret_cast<float4*>(&Bs[buf][akk][amc * 4]) = rb;
    } else {
      Bs[buf][aq * 4 + 0][arow] = rb.x; Bs[buf][aq * 4 + 1][arow] = rb.y;
      Bs[buf][aq * 4 + 2][arow] = rb.z; Bs[buf][aq * 4 + 3][arow] = rb.w;
    }
  };

  float acc[4][4];
#pragma unroll
  for (int i = 0; i < 4; ++i)
#pragma unroll
    for (int j = 0; j < 4; ++j) acc[i][j] = 0.f;

  const int nk = K / GBK;
  loadA(0); loadB(0); storeA(0); storeB(0);
  __syncthreads();

  for (int t = 0; t < nk; ++t) {
    const int cur = t & 1;
    if (t + 1 < nk) { loadA((t + 1) * GBK); loadB((t + 1) * GBK); }
#pragma unroll
    for (int kk = 0; kk < GBK; ++kk) {
      float a[4], b[4];
      *reinterpret_cast<float4*>(a) = *reinterpret_cast<const float4*>(&As[cur][kk][ty * 4]);
      *reinterpret_cast<float4*>(b) = *reinterpret_cast<const float4*>(&Bs[cur][kk][tx * 4]);
#pragma unroll
      for (int i = 0; i < 4; ++i)
#pragma unroll
        for (int j = 0; j < 4; ++j)
          acc[i][j] = fmaf(a[i], b[j], acc[i][j]);
    }
    if (t + 1 < nk) { storeA(cur ^ 1); storeB(cur ^ 1); }
    __syncthreads();
  }

#pragma unroll
  for (int i = 0; i < 4; ++i) {
    const int gm = bm + ty * 4 + i;
    const int gn0 = bn + tx * 4;
    float vv[4];
#pragma unroll
    for (int j = 0; j < 4; ++j) vv[j] = alpha * acc[i][j];
    if (Add) {
      const float4 ad = *reinterpret_cast<const float4*>(&Add[(size_t)gm * ldadd + gn0]);
      vv[0] += ad.x; vv[1] += ad.y; vv[2] += ad.z; vv[3] += ad.w;
    }
    if (addI) {
#pragma unroll
      for (int j = 0; j < 4; ++j) if (gm == gn0 + j) vv[j] += 1.f;
    }
    float4 v; v.x = vv[0]; v.y = vv[1]; v.z = vv[2]; v.w = vv[3];
    *reinterpret_cast<float4*>(&C[(size_t)gm * ldc + gn0]) = v;
  }
  (void)M; (void)N;
}

// sum ks partials (compact MxN each) + epilogue
__global__ __launch_bounds__(256)
void reduce_split_kernel(int N, int ldc, float* __restrict__ C,
                         const float* __restrict__ PS, long long MN, int ks,
                         float alpha, const float* __restrict__ Add, int ldadd,
                         int addI, int sym)
{
  long long i4 = ((long long)blockIdx.x * 256 + threadIdx.x) * 4;
  if (i4 >= MN) return;
  const int m = (int)(i4 / N), n = (int)(i4 % N);
  if (sym && (n >> 7) > (m >> 7)) return;
  float4 s = *reinterpret_cast<const float4*>(&PS[i4]);
  for (int z = 1; z < ks; ++z) {
    const float4 p = *reinterpret_cast<const float4*>(&PS[(size_t)z * MN + i4]);
    s.x += p.x; s.y += p.y; s.z += p.z; s.w += p.w;
  }
  float vv[4] = { alpha * s.x, alpha * s.y, alpha * s.z, alpha * s.w };
  if (Add) {
    const float4 ad = *reinterpret_cast<const float4*>(&Add[(size_t)m * ldadd + n]);
    vv[0] += ad.x; vv[1] += ad.y; vv[2] += ad.z; vv[3] += ad.w;
  }
  if (addI) {
#pragma unroll
    for (int j = 0; j < 4; ++j) if (m == n + j) vv[j] += 1.f;
  }
  float4 v; v.x = vv[0]; v.y = vv[1]; v.z = vv[2]; v.w = vv[3];
  *reinterpret_cast<float4*>(&C[(size_t)m * ldc + n]) = v;
}

// mirror lower triangle to upper: C[r][c] = C[c][r] for c > r. Tiled 32x32.
__global__ __launch_bounds__(256)
void mirror_kernel(int n, int ld, float* __restrict__ C)
{
  __shared__ float t[32][33];
  const int bx = (int)blockIdx.x, by = (int)blockIdx.y;
  if (by < bx) return;
  const int r0 = by * 32, c0 = bx * 32;
  const int tx = (int)threadIdx.x & 31, ty4 = ((int)threadIdx.x >> 5) * 4;
#pragma unroll
  for (int k = 0; k < 4; ++k)
    t[ty4 + k][tx] = C[(size_t)(r0 + ty4 + k) * ld + c0 + tx];
  __syncthreads();
  if (by == bx) {
#pragma unroll
    for (int k = 0; k < 4; ++k) {
      int rr = ty4 + k;
      if (tx > rr) C[(size_t)(c0 + rr) * ld + r0 + tx] = t[tx][rr];
    }
  } else {
#pragma unroll
    for (int k = 0; k < 4; ++k)
      C[(size_t)(c0 + ty4 + k) * ld + r0 + tx] = t[tx][ty4 + k];
  }
}

// sym: 0 = full; 1 = lower-only + mirror; 2 = lower-only, upper never read
template<int OPA, int OPB>
static void gemm_launch(hipStream_t st, int M, int N, int K,
                        const float* A, int lda, size_t zsA,
                        const float* B, int ldb, size_t zsB,
                        float* C, int ldc, size_t zsC,
                        float alpha, const float* Add, int ldadd, int addI,
                        int batch, int sym, int allow64)
{
  int ks = 1;
  if (batch == 1 && g_ps_ok && K >= 512) {
    int nbm = M / 128, nbn = N / 128;
    long long blocks = sym ? (long long)nbm * (nbm + 1) / 2 : (long long)nbm * nbn;
    long long MN = (long long)M * N;
    while (ks < 8 && blocks * ks < 512 && (K % (32 * ks)) == 0 && (long long)(ks * 2) * MN <= g_ps_cap)
      ks *= 2;
  }
  if (ks > 1) {
    const int Kp = K / ks;
    const long long MN = (long long)M * N;
    const size_t sA = (OPA == 0) ? (size_t)Kp : (size_t)Kp * lda;
    const size_t sB = (OPB == 0) ? (size_t)Kp * ldb : (size_t)Kp;
    dim3 grid(N / 128, M / 128, ks), blk(512);
    gemm_kernel<OPA, OPB><<<grid, blk, 0, st>>>(M, N, Kp, A, lda, B, ldb,
                                                g_ps, N, 1.f, nullptr, 0, 0, sA, sB, (size_t)MN, sym);
    reduce_split_kernel<<<(int)cdiv((int)(MN / 4), 256), 256, 0, st>>>(
        N, ldc, C, g_ps, MN, ks, alpha, Add, ldadd, addI, sym);
  } else {
    long long blocks128 = (long long)(M / 128) * (N / 128) * batch;
    if (allow64 && (M % 64) == 0 && (N % 64) == 0 && blocks128 < 64) {
      dim3 grid(N / 64, M / 64, batch), blk(256);
      gemm64_kernel<OPA, OPB><<<grid, blk, 0, st>>>(M, N, K, A, lda, B, ldb,
                                                    C, ldc, alpha, Add, ldadd, addI, zsA, zsB, zsC, sym);
    } else {
      dim3 grid(N / 128, M / 128, batch), blk(512);
      gemm_kernel<OPA, OPB><<<grid, blk, 0, st>>>(M, N, K, A, lda, B, ldb,
                                                  C, ldc, alpha, Add, ldadd, addI, zsA, zsB, zsC, sym);
    }
  }
  if (sym == 1) {
    dim3 mg(N / 32, M / 32);
    mirror_kernel<<<mg, 256, 0, st>>>(M, ldc, C);
  }
}

static void gemm_b(hipStream_t st, int opa, int opb, int M, int N, int K,
                   const float* A, int lda, size_t zsA,
                   const float* B, int ldb, size_t zsB,
                   float* C, int ldc, size_t zsC,
                   float alpha, const float* Add, int ldadd, int addI,
                   int batch, int sym = 0, int allow64 = 1)
{
  if (opa == 0 && opb == 0)
    gemm_launch<0,0>(st, M, N, K, A, lda, zsA, B, ldb, zsB, C, ldc, zsC, alpha, Add, ldadd, addI, batch, sym, allow64);
  else if (opa == 0 && opb == 1)
    gemm_launch<0,1>(st, M, N, K, A, lda, zsA, B, ldb, zsB, C, ldc, zsC, alpha, Add, ldadd, addI, batch, sym, allow64);
  else
    gemm_launch<1,0>(st, M, N, K, A, lda, zsA, B, ldb, zsB, C, ldc, zsC, alpha, Add, ldadd, addI, batch, sym, allow64);
}

static void gemm(hipStream_t st, int opa, int opb, int M, int N, int K,
                 const float* A, int lda, const float* B, int ldb,
                 float* C, int ldc, float alpha,
                 const float* Add, int ldadd, int addI, int sym = 0, int allow64 = 1)
{
  gemm_b(st, opa, opb, M, N, K, A, lda, 0, B, ldb, 0, C, ldc, 0, alpha, Add, ldadd, addI, 1, sym, allow64);
}

// ---------------------------------------------------------------------------
// Matvec helpers
// ---------------------------------------------------------------------------
__global__ __launch_bounds__(256)
void mv_n_kernel(int M, int K, const float* A, int lda, const float* x, float* y)
{
  int m = (int)blockIdx.x;
  if (m >= M) return;
  const float* row = A + (size_t)m * lda;
  float s = 0.f;
  for (int k = (int)threadIdx.x; k < K; k += 256) s += row[k] * x[k];
  __shared__ float red[256];
  red[threadIdx.x] = s;
  __syncthreads();
  for (int off = 128; off > 0; off >>= 1) {
    if ((int)threadIdx.x < off) red[threadIdx.x] += red[threadIdx.x + off];
    __syncthreads();
  }
  if (threadIdx.x == 0) y[m] = red[0];
}

// ---- column matvec (w = A^T x), two-stage row-split ----
__global__ __launch_bounds__(256)
void mv_t3_part_kernel(int Nrows, int Ncols, const float* __restrict__ A, int lda,
                       const float* __restrict__ x0, const float* __restrict__ x1,
                       const float* __restrict__ x2, float* __restrict__ PS, int RS)
{
  int e = (int)(blockIdx.x * 256 + threadIdx.x);
  if (e >= Ncols) return;
  int chunk = cdiv(Nrows, RS);
  int rs = (int)blockIdx.y;
  int n0 = rs * chunk, n1 = min(Nrows, n0 + chunk);
  float s0 = 0.f, s1 = 0.f, s2 = 0.f;
  for (int n = n0; n < n1; ++n) {
    float b = A[(size_t)n * lda + e];
    s0 += b * x0[n]; s1 += b * x1[n]; s2 += b * x2[n];
  }
  PS[((size_t)rs * 3 + 0) * Ncols + e] = s0;
  PS[((size_t)rs * 3 + 1) * Ncols + e] = s1;
  PS[((size_t)rs * 3 + 2) * Ncols + e] = s2;
}

__global__ __launch_bounds__(256)
void mv_t3_red_kernel(int Ncols, const float* __restrict__ PS, int RS,
                      float* w0, float* w1, float* w2)
{
  int e = (int)(blockIdx.x * 256 + threadIdx.x);
  if (e >= Ncols) return;
  float s0 = 0.f, s1 = 0.f, s2 = 0.f;
  for (int rs = 0; rs < RS; ++rs) {
    s0 += PS[((size_t)rs * 3 + 0) * Ncols + e];
    s1 += PS[((size_t)rs * 3 + 1) * Ncols + e];
    s2 += PS[((size_t)rs * 3 + 2) * Ncols + e];
  }
  w0[e] = s0; w1[e] = s1; w2[e] = s2;
}

__global__ __launch_bounds__(256)
void mv_t_part_kernel(int Nrows, int Ncols, const float* __restrict__ A, int lda,
                      const float* __restrict__ x, float* __restrict__ PS, int RS)
{
  int e = (int)(blockIdx.x * 256 + threadIdx.x);
  if (e >= Ncols) return;
  int chunk = cdiv(Nrows, RS);
  int rs = (int)blockIdx.y;
  int n0 = rs * chunk, n1 = min(Nrows, n0 + chunk);
  float s = 0.f;
  for (int n = n0; n < n1; ++n) s += A[(size_t)n * lda + e] * x[n];
  PS[(size_t)rs * Ncols + e] = s;
}

__global__ __launch_bounds__(256)
void mv_t_red_kernel(int Ncols, const float* __restrict__ PS, int RS,
                     const float* __restrict__ addv, float* w)
{
  int e = (int)(blockIdx.x * 256 + threadIdx.x);
  if (e >= Ncols) return;
  float s = 0.f;
  for (int rs = 0; rs < RS; ++rs) s += PS[(size_t)rs * Ncols + e];
  if (addv) s += addv[e];
  w[e] = s;
}

// single-stage fallbacks
__global__ __launch_bounds__(256)
void mv_t_kernel(int Nrows, int Ncols, const float* A, int lda,
                 const float* x, const float* addv, float* w)
{
  int e = (int)(blockIdx.x * blockDim.x + threadIdx.x);
  if (e >= Ncols) return;
  float s = 0.f;
  for (int n = 0; n < Nrows; ++n) s += A[(size_t)n * lda + e] * x[n];
  if (addv) s += addv[e];
  w[e] = s;
}

__global__ __launch_bounds__(256)
void mv_t3_kernel(int Nrows, int Ncols, const float* A, int lda,
                  const float* x0, const float* x1, const float* x2,
                  float* w0, float* w1, float* w2)
{
  int e = (int)(blockIdx.x * blockDim.x + threadIdx.x);
  if (e >= Ncols) return;
  float s0 = 0.f, s1 = 0.f, s2 = 0.f;
  for (int n = 0; n < Nrows; ++n) {
    float b = A[(size_t)n * lda + e];
    s0 += b * x0[n]; s1 += b * x1[n]; s2 += b * x2[n];
  }
  w0[e] = s0; w1[e] = s1; w2[e] = s2;
}

static void mv_t3(hipStream_t st, int Nrows, int Ncols, const float* A, int lda,
                  const float* x0, const float* x1, const float* x2,
                  float* w0, float* w1, float* w2)
{
  const int RS = 64;
  if (g_ps_ok && (long long)RS * 3 * Ncols <= g_ps_cap) {
    dim3 grid(cdiv(Ncols, 256), RS);
    mv_t3_part_kernel<<<grid, 256, 0, st>>>(Nrows, Ncols, A, lda, x0, x1, x2, g_ps, RS);
    mv_t3_red_kernel<<<cdiv(Ncols, 256), 256, 0, st>>>(Ncols, g_ps, RS, w0, w1, w2);
  } else {
    mv_t3_kernel<<<cdiv(Ncols, 256), 256, 0, st>>>(Nrows, Ncols, A, lda, x0, x1, x2, w0, w1, w2);
  }
}

static void mv_t_add(hipStream_t st, int Nrows, int Ncols, const float* A, int lda,
                     const float* x, const float* addv, float* w)
{
  const int RS = 64;
  if (g_ps_ok && (long long)RS * Ncols <= g_ps_cap) {
    dim3 grid(cdiv(Ncols, 256), RS);
    mv_t_part_kernel<<<grid, 256, 0, st>>>(Nrows, Ncols, A, lda, x, g_ps, RS);
    mv_t_red_kernel<<<cdiv(Ncols, 256), 256, 0, st>>>(Ncols, g_ps, RS, addv, w);
  } else {
    mv_t_kernel<<<cdiv(Ncols, 256), 256, 0, st>>>(Nrows, Ncols, A, lda, x, addv, w);
  }
}

// ---------------------------------------------------------------------------
// elementwise helpers
// ---------------------------------------------------------------------------
__global__ __launch_bounds__(256)
void scale_cols_kernel(long long total, int E, const float* B, const float* sv, float* out)
{
  long long i = (long long)blockIdx.x * blockDim.x + threadIdx.x;
  if (i < total) {
    int e = (int)(i % E);
    out[i] = B[i] * sv[e];
  }
}

__global__ __launch_bounds__(256)
void build_h_kernel(long long total, int E,
                    const float* B, const float* LB, const float* L2B,
                    const float* w0, const float* w1, const float* w2,
                    const float* a, float* H)
{
  long long i = (long long)blockIdx.x * blockDim.x + threadIdx.x;
  if (i < total) {
    int e = (int)(i % E);
    float a1 = a[1], a2 = a[2], a3 = a[3];
    float b = B[i], lb = LB[i], l2b = L2B[i];
    H[i] = w0[e] * (a1 * b + a2 * lb + a3 * l2b)
         + w1[e] * (a2 * b + a3 * lb)
         + w2[e] * (a3 * b);
  }
}

__global__ __launch_bounds__(256)
void poly_resid_kernel(int Nn, const float* a, const float* q,
                       const float* c1, const float* c2, const float* c3,
                       const float* y, float* resid)
{
  int n = (int)(blockIdx.x * blockDim.x + threadIdx.x);
  if (n < Nn)
    resid[n] = y[n] - (a[0] * q[n] + a[1] * c1[n] + a[2] * c2[n] + a[3] * c3[n]);
}

__global__ __launch_bounds__(256)
void fzero_kernel(float* p, long long n)
{
  long long i = (long long)blockIdx.x * blockDim.x + threadIdx.x;
  if (i < n) p[i] = 0.f;
}

// ---------------------------------------------------------------------------
// fused index setup (single block)
// ---------------------------------------------------------------------------
__global__ __launch_bounds__(1024)
void setup_idx_kernel(const void* __restrict__ connRaw, int Kc, int E,
                      const float* __restrict__ s_upd,
                      int* conn32, int* invc, float* s2, float* outS)
{
  const int tid = (int)threadIdx.x;
  const unsigned* u = (const unsigned*)connRaw;
  const bool is64 = (u[1] | u[3] | u[5] | u[7]) == 0u;
  for (int i = tid; i < Kc; i += 1024)
    conn32[i] = is64 ? (int)((const long long*)connRaw)[i] : ((const int*)connRaw)[i];
  for (int e = tid; e < E; e += 1024) invc[e] = -1;
  __syncthreads();
  for (int i = tid; i < Kc; i += 1024) invc[conn32[i]] = i;
  __syncthreads();
  for (int e = tid; e < E; e += 1024) {
    float v = (invc[e] >= 0) ? s_upd[e] : 0.f;
    s2[e] = v;
    outS[e] = v;
  }
}

// fused gather of H2 (Nn x Kc) and Scc (Kc x Kc)
__global__ __launch_bounds__(256)
void gather2_kernel(int Nn, int Kc, int E,
                    const float* __restrict__ H2full, const float* __restrict__ Sig,
                    const int* __restrict__ conn, float* H2, float* Scc)
{
  const long long NK = (long long)Nn * Kc;
  const long long KK = (long long)Kc * Kc;
  long long i = (long long)blockIdx.x * blockDim.x + threadIdx.x;
  if (i < NK) {
    int n = (int)(i / Kc), c = (int)(i % Kc);
    H2[i] = H2full[(size_t)n * E + conn[c]];
  } else if (i < NK + KK) {
    long long j = i - NK;
    int r = (int)(j / Kc), c = (int)(j % Kc);
    Scc[j] = Sig[(size_t)conn[r] * E + conn[c]];
  }
}

__global__ __launch_bounds__(256)
void write_sigma_out_kernel(long long total, int E, const float* Small, int Kc,
                            const int* inv, float* out)
{
  long long i = (long long)blockIdx.x * blockDim.x + threadIdx.x;
  if (i < total) {
    int r = (int)(i / E), c = (int)(i % E);
    int ir = inv[r], ic = inv[c];
    out[i] = (ir >= 0 && ic >= 0) ? Small[(size_t)ir * Kc + ic] : 0.f;
  }
}

// ---------------------------------------------------------------------------
// Fused Cholesky leaf (1024 threads): factor 128x128 diag block AND invert it.
// 8-wide panels; wave-synchronous factor panel; rank-8 trailing updates.
// Writes ONLY invL (to Linv at (off,off)).
// ---------------------------------------------------------------------------
__global__ __launch_bounds__(1024)
void chol_leaf_kernel(const float* __restrict__ S, int lda, int off,
                      float* __restrict__ Linv, int ldi)
{
  __shared__ float T[128][132];
  __shared__ float X[128][132];
  const int tid = (int)threadIdx.x;
  const float* Ab = S + (size_t)off * lda + off;
  for (int idx = tid; idx < 128 * 32; idx += 1024) {
    int r = idx >> 5, c4 = (idx & 31) << 2;
    const float4 v = *reinterpret_cast<const float4*>(&Ab[(size_t)r * lda + c4]);
    *reinterpret_cast<float4*>(&T[r][c4]) = v;
    X[r][c4 + 0] = (r == c4 + 0) ? 1.f : 0.f;
    X[r][c4 + 1] = (r == c4 + 1) ? 1.f : 0.f;
    X[r][c4 + 2] = (r == c4 + 2) ? 1.f : 0.f;
    X[r][c4 + 3] = (r == c4 + 3) ? 1.f : 0.f;
  }
  __syncthreads();
  const int wave = tid >> 6;
  const int lane = tid & 63;
  const int g32 = tid >> 5, l32 = tid & 31;

  for (int j0 = 0; j0 < 128; j0 += 8) {
    if (wave == 0) {
      for (int t = 0; t < 8; ++t) {
        const int j = j0 + t;
#pragma unroll
        for (int rr = 0; rr < 2; ++rr) {
          const int r = lane + 64 * rr;
          if (r >= j) {
            float s = T[r][j];
            for (int u = 0; u < t; ++u) s -= T[r][j0 + u] * T[j][j0 + u];
            T[r][j] = s;
          }
        }
        const float d = sqrtf(T[j][j]);
        const float inv = 1.f / d;
#pragma unroll
        for (int rr = 0; rr < 2; ++rr) {
          const int r = lane + 64 * rr;
          if (r > j) T[r][j] *= inv;
          else if (r == j) T[j][j] = d;
        }
      }
    }
    __syncthreads();
    for (int r = j0 + 8 + g32; r < 128; r += 32) {
      const float4 a0 = *reinterpret_cast<const float4*>(&T[r][j0]);
      const float4 a1 = *reinterpret_cast<const float4*>(&T[r][j0 + 4]);
      for (int c = j0 + 8 + l32; c <= r; c += 32) {
        const float4 b0 = *reinterpret_cast<const float4*>(&T[c][j0]);
        const float4 b1 = *reinterpret_cast<const float4*>(&T[c][j0 + 4]);
        T[r][c] -= a0.x * b0.x + a0.y * b0.y + a0.z * b0.z + a0.w * b0.w
                 + a1.x * b1.x + a1.y * b1.y + a1.z * b1.z + a1.w * b1.w;
      }
    }
    __syncthreads();
  }

  for (int j0 = 0; j0 < 128; j0 += 8) {
    if (tid < 128) {
      const int c = tid;
      float xp[8];
#pragma unroll
      for (int t = 0; t < 8; ++t) {
        const int j = j0 + t;
        if (c <= j) {
          float s = X[j][c];
          for (int u = 0; u < t; ++u) s -= T[j][j0 + u] * xp[u];
          xp[t] = s / T[j][j];
          X[j][c] = xp[t];
        } else {
          xp[t] = 0.f;
        }
      }
    }
    __syncthreads();
    for (int i = j0 + 8 + g32; i < 128; i += 32) {
      const float4 a0 = *reinterpret_cast<const float4*>(&T[i][j0]);
      const float4 a1 = *reinterpret_cast<const float4*>(&T[i][j0 + 4]);
      for (int c = l32; c <= j0 + 7; c += 32) {
        X[i][c] -= a0.x * X[j0][c]     + a0.y * X[j0 + 1][c]
                 + a0.z * X[j0 + 2][c] + a0.w * X[j0 + 3][c]
                 + a1.x * X[j0 + 4][c] + a1.y * X[j0 + 5][c]
                 + a1.z * X[j0 + 6][c] + a1.w * X[j0 + 7][c];
      }
    }
    __syncthreads();
  }

  float* Ob = Linv + (size_t)off * ldi + off;
  for (int idx = tid; idx < 128 * 32; idx += 1024) {
    int r = idx >> 5, c4 = (idx & 31) << 2;
    float4 v;
    v.x = X[r][c4]; v.y = X[r][c4 + 1]; v.z = X[r][c4 + 2]; v.w = X[r][c4 + 3];
    *reinterpret_cast<float4*>(&Ob[(size_t)r * ldi + c4]) = v;
  }
}

// ---------------------------------------------------------------------------
// SPD inverse: S (n x n, lower valid) -> Sinv (full). S destroyed.
// ---------------------------------------------------------------------------
static void spd_inverse(hipStream_t st, float* S, float* Linv, float* Sinv, float* TT, int n)
{
  long long nn = (long long)n * n;
  fzero_kernel<<<cdiv((int)nn, 256), 256, 0, st>>>(Linv, nn);
  for (int off = 0; off < n; off += 128) {
    chol_leaf_kernel<<<1, 1024, 0, st>>>(S, n, off, Linv, n);
    int mrem = n - off - 128;
    if (mrem > 0) {
      float* P = S + (size_t)(off + 128) * n + off;
      // in-place TRSM-apply: must stay 128-tile (64-tile would race on shared rows)
      gemm(st, 0, 1, mrem, 128, 128, P, n, Linv + (size_t)off * (n + 1), n, P, n, 1.f, nullptr, 0, 0, 0, 0);
      float* Ct = S + (size_t)(off + 128) * (n + 1);
      gemm(st, 0, 1, mrem, mrem, 128, P, n, P, n, Ct, n, -1.f, Ct, n, 0, 2);  // SYRK, lower only
    }
  }
  for (int m = 128; m < n; m <<= 1) {
    int pairs = n / (2 * m);
    size_t zs = (size_t)2 * m * (n + 1);
    gemm_b(st, 0, 0, m, m, m, S + (size_t)m * n, n, zs, Linv, n, zs,
           TT, m, (size_t)m * m, 1.f, nullptr, 0, 0, pairs, 0);
    gemm_b(st, 0, 0, m, m, m, Linv + (size_t)m * (n + 1), n, zs, TT, m, (size_t)m * m,
           Linv + (size_t)m * n, n, zs, -1.f, nullptr, 0, 0, pairs, 0);
  }
  gemm(st, 1, 0, n, n, n, Linv, n, Linv, n, Sinv, n, 1.f, nullptr, 0, 0, 1);  // sym + mirror
}

// ---------------------------------------------------------------------------
extern "C" void kernel_launch(void* const* d_in, const int* in_sizes, int n_in,
                              void* d_out, int out_size, void* d_ws, size_t ws_size,
                              hipStream_t stream)
{
  const float* F  = (const float*)d_in[0];
  const float* B  = (const float*)d_in[1];
  const float* V  = (const float*)d_in[2];
  const float* W  = (const float*)d_in[3];
  const float* Sg = (const float*)d_in[4];
  const float* sv = (const float*)d_in[5];
  const float* av = (const float*)d_in[6];
  const float* q  = (const float*)d_in[7];
  const float* y  = (const float*)d_in[8];
  const void*  connRaw = d_in[10];

  const int E  = in_sizes[5];
  const int Nn = in_sizes[7];
  const int Kc = in_sizes[10];

  const size_t EE = (size_t)E * E;
  const size_t NE = (size_t)Nn * E;
  const size_t NN = (size_t)Nn * Nn;
  const size_t NK = (size_t)Nn * Kc;
  const size_t KK = (size_t)Kc * Kc;

  float* ws = (float*)d_ws;
  float* EE_A = ws;
  float* EE_B = EE_A + EE;
  float* NE_1 = EE_B + EE;
  float* NE_2 = NE_1 + NE;   // Y / TT / U / T10 (time-disjoint)
  float* NE_3 = NE_2 + NE;
  float* NN_1 = NE_3 + NE;   // L / S factor
  float* NN_2 = NN_1 + NN;   // Linv
  float* NN_3 = NN_2 + NN;   // Sinv
  float* vec  = NN_3 + NN;
  float* s1    = vec;            vec += E;
  float* c1    = vec;            vec += Nn;
  float* c2    = vec;            vec += Nn;
  float* c3    = vec;            vec += Nn;
  float* w0    = vec;            vec += E;
  float* w1    = vec;            vec += E;
  float* w2    = vec;            vec += E;
  float* resid = vec;            vec += Nn;
  float* s_upd = vec;            vec += E;
  float* s2    = vec;            vec += E;
  int* conn32  = (int*)vec;
  int* invc    = conn32 + Kc;
  float* after_ints = (float*)(invc + E);

  // shared scratch (split-K partials + matvec partials), gated on ws_size
  uintptr_t psa = ((uintptr_t)after_ints + 255) & ~(uintptr_t)255;
  g_ps = (float*)psa;
  g_ps_ok = 0;
  for (long long capf = 4 * (long long)EE; capf >= 2 * (long long)EE; capf /= 2) {
    size_t need = (size_t)((char*)(g_ps + capf) - (char*)d_ws);
    if (need <= ws_size) { g_ps_cap = capf; g_ps_ok = 1; break; }
  }

  float* outS   = (float*)d_out;   // E
  float* outSig = outS + E;        // E*E; scratch until final write
  float* EE_C   = outSig;
  float* TT     = NE_2;            // bisection temp (dead region at that time)

  const long long totNE = (long long)Nn * E;
  const long long totEE = (long long)E * E;

  // ---- stage 1 ----
  mv_n_kernel<<<E, 256, 0, stream>>>(E, E, F, E, sv, s1);                        // s1 = F s
  gemm(stream, 0, 0, E, E, E, F, E, Sg, E, EE_A, E, 1.f, nullptr, 0, 0, 0);      // G1 = F Sigma
  gemm(stream, 0, 1, E, E, E, EE_A, E, F, E, EE_B, E, 1.f, V, E, 0, 1);          // Sigma1 = G1 F^T + V (sym)
  scale_cols_kernel<<<cdiv((int)totNE, 256), 256, 0, stream>>>(totNE, E, B, s1, NE_1); // Bs
  gemm(stream, 0, 1, Nn, Nn, E, NE_1, E, B, E, NN_1, Nn, 1.f, nullptr, 0, 0, 1); // L = Bs B^T (sym+mirror)
  mv_n_kernel<<<Nn, 256, 0, stream>>>(Nn, Nn, NN_1, Nn, q, c1);
  mv_n_kernel<<<Nn, 256, 0, stream>>>(Nn, Nn, NN_1, Nn, c1, c2);
  mv_n_kernel<<<Nn, 256, 0, stream>>>(Nn, Nn, NN_1, Nn, c2, c3);
  mv_t3(stream, Nn, E, B, E, q, c1, c2, w0, w1, w2);
  poly_resid_kernel<<<cdiv(Nn, 256), 256, 0, stream>>>(Nn, av, q, c1, c2, c3, y, resid);
  gemm(stream, 0, 0, Nn, E, Nn, NN_1, Nn, B, E, NE_1, E, 1.f, nullptr, 0, 0, 0); // LB
  gemm(stream, 0, 0, Nn, E, Nn, NN_1, Nn, NE_1, E, NE_2, E, 1.f, nullptr, 0, 0, 0); // L2B
  build_h_kernel<<<cdiv((int)totNE, 256), 256, 0, stream>>>(totNE, E, B, NE_1, NE_2, w0, w1, w2, av, NE_3); // H
  gemm(stream, 0, 0, Nn, E, E, NE_3, E, EE_B, E, NE_1, E, 1.f, nullptr, 0, 0, 0);// T2 = H Sigma1
  gemm(stream, 0, 1, Nn, Nn, E, NE_1, E, NE_3, E, NN_1, Nn, 1.f, W, Nn, 0, 2);   // S = T2 H^T + W (lower only)
  spd_inverse(stream, NN_1, NN_2, NN_3, TT, Nn);                                 // Sinv in NN_3
  gemm(stream, 0, 0, Nn, E, Nn, NN_3, Nn, NE_1, E, NE_2, E, 1.f, nullptr, 0, 0, 0); // Y = Sinv T2
  mv_t_add(stream, Nn, E, NE_2, E, resid, s1, s_upd);                            // s_upd = s1 + Y^T resid
  // Joseph form without forming ImKH (K = Y^T):
  gemm(stream, 1, 0, E, E, Nn, NE_2, E, NE_1, E, EE_A, E, -1.f, EE_B, E, 0, 0);  // T3 = Sigma1 - Y^T T2
  gemm(stream, 0, 1, E, Nn, E, EE_A, E, NE_3, E, NE_1, Nn, 1.f, nullptr, 0, 0, 0); // U = T3 H^T
  gemm(stream, 0, 0, E, E, Nn, NE_1, Nn, NE_2, E, EE_C, E, -1.f, EE_A, E, 0, 1); // T4 = T3 - U Y (sym)
  gemm(stream, 1, 0, E, Nn, Nn, NE_2, E, W, Nn, NE_1, Nn, 1.f, nullptr, 0, 0, 0);// T5 = Y^T W
  gemm(stream, 0, 0, E, E, Nn, NE_1, Nn, NE_2, E, EE_B, E, 1.f, EE_C, E, 0, 1);  // Sigma2 = T5 Y + T4 (sym)

  // ---- masking / stage 2 ----
  setup_idx_kernel<<<1, 1024, 0, stream>>>(connRaw, Kc, E, s_upd, conn32, invc, s2, outS);

  scale_cols_kernel<<<cdiv((int)totNE, 256), 256, 0, stream>>>(totNE, E, B, s2, NE_1); // Bs2
  gemm(stream, 0, 1, Nn, Nn, E, NE_1, E, B, E, NN_1, Nn, 1.f, nullptr, 0, 0, 1); // L2 (sym+mirror)
  mv_n_kernel<<<Nn, 256, 0, stream>>>(Nn, Nn, NN_1, Nn, q, c1);
  mv_n_kernel<<<Nn, 256, 0, stream>>>(Nn, Nn, NN_1, Nn, c1, c2);
  mv_t3(stream, Nn, E, B, E, q, c1, c2, w0, w1, w2);
  gemm(stream, 0, 0, Nn, E, Nn, NN_1, Nn, B, E, NE_1, E, 1.f, nullptr, 0, 0, 0); // L2 B
  gemm(stream, 0, 0, Nn, E, Nn, NN_1, Nn, NE_1, E, NE_2, E, 1.f, nullptr, 0, 0, 0); // L2^2 B
  build_h_kernel<<<cdiv((int)totNE, 256), 256, 0, stream>>>(totNE, E, B, NE_1, NE_2, w0, w1, w2, av, NE_3); // H2full
  gather2_kernel<<<cdiv((int)(NK + KK), 256), 256, 0, stream>>>(Nn, Kc, E, NE_3, EE_B, conn32, EE_A, EE_A + NK); // H2, Scc
  gemm(stream, 0, 0, Nn, Kc, Kc, EE_A, Kc, EE_A + NK, Kc, EE_B, Kc, 1.f, nullptr, 0, 0, 0); // T7 = H2 Scc
  gemm(stream, 0, 1, Nn, Nn, Kc, EE_B, Kc, EE_A, Kc, NN_1, Nn, 1.f, W, Nn, 0, 2);// S2 = T7 H2^T + W (lower only)
  spd_inverse(stream, NN_1, NN_2, NN_3, TT, Nn);                                 // Sinv2 in NN_3
  gemm(stream, 0, 0, Nn, Kc, Nn, NN_3, Nn, EE_B, Kc, NE_1, Kc, 1.f, nullptr, 0, 0, 0);  // Y2 = Sinv2 T7
  gemm(stream, 1, 0, Kc, Kc, Nn, NE_1, Kc, EE_A, Kc, EE_C, Kc, -1.f, nullptr, 0, 1, 0); // ImKH2 = I - Y2^T H2
  gemm(stream, 0, 0, Kc, Kc, Kc, EE_C, Kc, EE_A + NK, Kc, EE_C + KK, Kc, 1.f, nullptr, 0, 0, 0); // T8 = ImKH2 Scc
  gemm(stream, 0, 1, Kc, Kc, Kc, EE_C + KK, Kc, EE_C, Kc, EE_A + NK, Kc, 1.f, nullptr, 0, 0, 1); // T9 (sym)
  gemm(stream, 1, 0, Kc, Nn, Nn, NE_1, Kc, W, Nn, NE_2, Nn, 1.f, nullptr, 0, 0, 0); // T10 = Y2^T W
  gemm(stream, 0, 0, Kc, Kc, Nn, NE_2, Nn, NE_1, Kc, EE_A + NK, Kc, 1.f, EE_A + NK, Kc, 0, 1); // Small (sym)

  write_sigma_out_kernel<<<cdiv((int)totEE, 256), 256, 0, stream>>>(totEE, E, EE_A + NK, Kc, invc, outSig);

  (void)n_in; (void)out_size; (void)ws_size;
}